// Round 1
// baseline (200.860 us; speedup 1.0000x reference)
//
#include <hip/hip_runtime.h>

// _GSPostProcessor: out = D^{-1/2} (topk20(relu(A) + dope*1e-4)*relu(A) + I) D^{-1/2}
// B=16, N=2048, K=20.  Output dense fp32, <=21 nonzeros per row.
// Pass 1: wave-per-row exact top-20 + d_inv  -> staged in d_ws (5.4 MB)
// Pass 2: block-per-row LDS scatter -> dense coalesced write (covers all of d_out)

static constexpr int N    = 2048;
static constexpr int KSEL = 20;
static constexpr int NR   = 16 * 2048;   // B*N rows

// Branchless stable insertion of (vc, jc) into sorted-desc top-4 (ties: earlier/lower j stays above).
__device__ __forceinline__ void ins4(float vc, int jc,
                                     float& t0, float& t1, float& t2, float& t3,
                                     int& j0, int& j1, int& j2, int& j3) {
  bool b0 = vc > t0;
  float d0 = b0 ? t0 : vc; int e0 = b0 ? j0 : jc;
  t0 = b0 ? vc : t0;       j0 = b0 ? jc : j0;
  bool b1 = d0 > t1;
  float d1 = b1 ? t1 : d0; int e1 = b1 ? j1 : e0;
  t1 = b1 ? d0 : t1;       j1 = b1 ? e0 : j1;
  bool b2 = d1 > t2;
  float d2 = b2 ? t2 : d1; int e2 = b2 ? j2 : e1;
  t2 = b2 ? d1 : t2;       j2 = b2 ? e1 : j2;
  bool b3 = d2 > t3;
  t3 = b3 ? d2 : t3;       j3 = b3 ? e2 : j3;
}

// One 64-lane wave finds the exact top-20 of v[j] = relu(A[j]) + dope[j]*1e-4 over j in [0,2048),
// jax.lax.top_k semantics (value desc, index asc on ties).
// Returns: lane t (t<20) holds the round-t selected column index.
__device__ __forceinline__ int wave_topk(const float* __restrict__ Arow,
                                         const float* __restrict__ Drow,
                                         int lane) {
  // Each lane owns 32 elements: j = c4*256 + lane*4 + q  (c4<8, q<4), ascending j per lane.
  float v[32];
  const float4* A4 = reinterpret_cast<const float4*>(Arow);
  const float4* D4 = reinterpret_cast<const float4*>(Drow);
#pragma unroll
  for (int c4 = 0; c4 < 8; ++c4) {
    float4 a = A4[c4 * 64 + lane];
    float4 d = D4[c4 * 64 + lane];
    // match numpy exactly: separate round for mul and add (no fma contraction)
    v[c4 * 4 + 0] = __fadd_rn(fmaxf(a.x, 0.0f), __fmul_rn(d.x, 1e-4f));
    v[c4 * 4 + 1] = __fadd_rn(fmaxf(a.y, 0.0f), __fmul_rn(d.y, 1e-4f));
    v[c4 * 4 + 2] = __fadd_rn(fmaxf(a.z, 0.0f), __fmul_rn(d.z, 1e-4f));
    v[c4 * 4 + 3] = __fadd_rn(fmaxf(a.w, 0.0f), __fmul_rn(d.w, 1e-4f));
  }

  // Per-lane sorted top-4 cache (values are >= 0; -1 is the "empty" sentinel).
  float t0 = -1.f, t1 = -1.f, t2 = -1.f, t3 = -1.f;
  int   j0 = 0,    j1 = 0,    j2 = 0,    j3 = 0;
#pragma unroll
  for (int c = 0; c < 32; ++c) {
    int jc = ((c >> 2) << 8) | (lane << 2) | (c & 3);
    ins4(v[c], jc, t0, t1, t2, t3, j0, j1, j2, j3);
  }

  unsigned consumed = 0;   // bit c set -> element c already extracted
  int jmine = 0;
#pragma unroll 1
  for (int it = 0; it < KSEL; ++it) {
    // Rare: a lane supplied 4 winners -> rebuild its cache from unconsumed elements.
    if (__any(t0 < 0.0f)) {
      if (t0 < 0.0f) {
        t0 = t1 = t2 = t3 = -1.f; j0 = j1 = j2 = j3 = 0;
#pragma unroll
        for (int c = 0; c < 32; ++c) {
          float vc = ((consumed >> c) & 1u) ? -1.0f : v[c];
          int jc = ((c >> 2) << 8) | (lane << 2) | (c & 3);
          ins4(vc, jc, t0, t1, t2, t3, j0, j1, j2, j3);
        }
      }
    }
    // wave argmax of cache heads; tie -> min index
    float m = t0;
#pragma unroll
    for (int off = 32; off; off >>= 1) m = fmaxf(m, __shfl_xor(m, off));
    int cj = (t0 == m) ? j0 : 0x7fffffff;
#pragma unroll
    for (int off = 32; off; off >>= 1) cj = min(cj, __shfl_xor(cj, off));
    if (lane == it) jmine = cj;
    // owner lane (encoded in j) consumes its head
    if (((cj >> 2) & 63) == lane) {
      int c = ((cj >> 8) << 2) | (cj & 3);
      consumed |= (1u << c);
      t0 = t1; j0 = j1; t1 = t2; j1 = j2; t2 = t3; j2 = j3; t3 = -1.f; j3 = 0;
    }
  }
  return jmine;
}

__global__ void __launch_bounds__(256)
topk_pass1(const float* __restrict__ A, const float* __restrict__ D,
           float* __restrict__ wval, int* __restrict__ widx,
           float* __restrict__ wdinv, int fullStore) {
  int lane = threadIdx.x & 63;
  int r = blockIdx.x * 4 + (threadIdx.x >> 6);
  size_t base = (size_t)r * N;
  int jm = wave_topk(A + base, D + base, lane);
  float val = 0.0f;
  if (lane < KSEL) val = fmaxf(A[base + jm], 0.0f);  // exact relu value (L2 hit)
  float s = (lane < KSEL) ? val : 0.0f;
#pragma unroll
  for (int off = 32; off; off >>= 1) s += __shfl_xor(s, off);
  float dinv = (float)(1.0 / sqrt(1.0 + (double)s));  // row sum >= 1, never inf
  if (fullStore && lane < KSEL) {
    wval[r * KSEL + lane] = val;
    widx[r * KSEL + lane] = jm;
  }
  if (lane == 0) wdinv[r] = dinv;
}

__global__ void __launch_bounds__(256)
scatter_pass2(const float* __restrict__ wval, const int* __restrict__ widx,
              const float* __restrict__ wdinv, float* __restrict__ out) {
  __shared__ float row[N];
  int r = blockIdx.x;
  int i = r & (N - 1);
  int tid = threadIdx.x;
  float4* rv = reinterpret_cast<float4*>(row);
  float4 z = make_float4(0.f, 0.f, 0.f, 0.f);
  rv[tid] = z;
  rv[tid + 256] = z;
  __syncthreads();
  float di = wdinv[r];
  if (tid < KSEL) {
    int j   = widx[r * KSEL + tid];
    float v = wval[r * KSEL + tid];
    float dj = wdinv[(r & ~(N - 1)) + j];
    atomicAdd(&row[j], di * v * dj);          // may collide with diagonal only
  } else if (tid == KSEL) {
    atomicAdd(&row[i], di * di);              // the +I term
  }
  __syncthreads();
  float4* o4 = reinterpret_cast<float4*>(out + (size_t)r * N);
  o4[tid] = rv[tid];
  o4[tid + 256] = rv[tid + 256];
}

// Fallback if d_ws is too small for full staging: recompute topk in pass 2 (only needs 128KB for d_inv).
__global__ void __launch_bounds__(256)
fallback_pass2(const float* __restrict__ A, const float* __restrict__ D,
               const float* __restrict__ wdinv, float* __restrict__ out) {
  __shared__ float rows[4][N];
  int lane = threadIdx.x & 63;
  int w = threadIdx.x >> 6;
  int r = blockIdx.x * 4 + w;
  size_t base = (size_t)r * N;
  int i = r & (N - 1);
  int jm = wave_topk(A + base, D + base, lane);
  float val = 0.0f;
  if (lane < KSEL) val = fmaxf(A[base + jm], 0.0f);
  float s = (lane < KSEL) ? val : 0.0f;
#pragma unroll
  for (int off = 32; off; off >>= 1) s += __shfl_xor(s, off);
  float di = (float)(1.0 / sqrt(1.0 + (double)s));
  float4* rv = reinterpret_cast<float4*>(rows[w]);
  float4 z = make_float4(0.f, 0.f, 0.f, 0.f);
#pragma unroll
  for (int q = 0; q < 8; ++q) rv[q * 64 + lane] = z;
  __syncthreads();
  if (lane < KSEL) {
    float dj = wdinv[(r & ~(N - 1)) + jm];
    atomicAdd(&rows[w][jm], di * val * dj);
  } else if (lane == KSEL) {
    atomicAdd(&rows[w][i], di * di);
  }
  __syncthreads();
  float4* o4 = reinterpret_cast<float4*>(out + base);
#pragma unroll
  for (int q = 0; q < 8; ++q) o4[q * 64 + lane] = rv[q * 64 + lane];
}

extern "C" void kernel_launch(void* const* d_in, const int* in_sizes, int n_in,
                              void* d_out, int out_size, void* d_ws, size_t ws_size,
                              hipStream_t stream) {
  const float* A = (const float*)d_in[0];
  const float* D = (const float*)d_in[1];
  float* out = (float*)d_out;
  char* ws = (char*)d_ws;
  size_t bytes_val  = (size_t)NR * KSEL * sizeof(float);
  size_t bytes_idx  = (size_t)NR * KSEL * sizeof(int);
  size_t bytes_dinv = (size_t)NR * sizeof(float);
  if (ws_size >= bytes_val + bytes_idx + bytes_dinv) {
    float* wval  = (float*)ws;
    int*   widx  = (int*)(ws + bytes_val);
    float* wdinv = (float*)(ws + bytes_val + bytes_idx);
    topk_pass1<<<NR / 4, 256, 0, stream>>>(A, D, wval, widx, wdinv, 1);
    scatter_pass2<<<NR, 256, 0, stream>>>(wval, widx, wdinv, out);
  } else {
    float* wdinv = (float*)ws;
    topk_pass1<<<NR / 4, 256, 0, stream>>>(A, D, nullptr, nullptr, wdinv, 0);
    fallback_pass2<<<NR / 4, 256, 0, stream>>>(A, D, wdinv, out);
  }
}